// Round 17
// baseline (153.223 us; speedup 1.0000x reference)
//
#include <hip/hip_runtime.h>
#include <hip/hip_bf16.h>
#include <stdint.h>

typedef __bf16 bf16x8 __attribute__((ext_vector_type(8)));
typedef __bf16 bf16x4 __attribute__((ext_vector_type(4)));
typedef float f32x4 __attribute__((ext_vector_type(4)));

#define DMODEL 1024
#define SEQ    2048
#define NHEAD  16
#define DK     64
#define MTOT   4096
#define KDIM   1024

#define DRAIN_VM_LGKM() asm volatile("s_waitcnt vmcnt(0) lgkmcnt(0)" ::: "memory")
#define DRAIN_LGKM()    asm volatile("s_waitcnt lgkmcnt(0)" ::: "memory")

__device__ __forceinline__ void gl2lds16(const void* g, void* l) {
  __builtin_amdgcn_global_load_lds((__attribute__((address_space(1))) void*)(g),
                                   (__attribute__((address_space(3))) void*)(l),
                                   16, 0, 0);
}

// ---------------- prep: cvt3 grid-stride (blocks 0..3071) + transpose4 (3072..7167) ----------------
__global__ __launch_bounds__(256) void k_prep(const float* __restrict__ q,
                                              const float* __restrict__ k,
                                              const float* __restrict__ v,
                                              __bf16* __restrict__ oq,
                                              __bf16* __restrict__ ok,
                                              __bf16* __restrict__ ov,
                                              const float* __restrict__ w0,
                                              const float* __restrict__ w1,
                                              const float* __restrict__ w2,
                                              const float* __restrict__ w3,
                                              __bf16* __restrict__ t0,
                                              __bf16* __restrict__ t1,
                                              __bf16* __restrict__ t2,
                                              __bf16* __restrict__ t3) {
  __shared__ float tile[32][33];
  const int bid = blockIdx.x;
  if (bid < 3072) {                        // f32 -> bf16 convert, q/k/v (grid-stride x4)
    const int which = bid >> 10;           // 0..2
    const float* in = which == 0 ? q : (which == 1 ? k : v);
    __bf16* out = which == 0 ? oq : (which == 1 ? ok : ov);
    int i = (bid & 1023) * 256 + threadIdx.x;   // 1M float4 per input
    #pragma unroll
    for (int it = 0; it < 4; ++it, i += 262144) {
      const float4 f = ((const float4*)in)[i];
      bf16x4 o = { (__bf16)f.x, (__bf16)f.y, (__bf16)f.z, (__bf16)f.w };
      ((bf16x4*)out)[i] = o;
    }
  } else {                                 // W [K][N] f32 -> WT [N][K] bf16
    const int b2 = bid - 3072;             // 0..4095
    const int z = b2 >> 10;
    const int t = b2 & 1023;
    const float* W = z == 0 ? w0 : (z == 1 ? w1 : (z == 2 ? w2 : w3));
    __bf16* WT = z == 0 ? t0 : (z == 1 ? t1 : (z == 2 ? t2 : t3));
    const int n0 = (t & 31) * 32, k0 = (t >> 5) * 32;
    const int tx = threadIdx.x & 31, ty = threadIdx.x >> 5;
    #pragma unroll
    for (int i = ty; i < 32; i += 8)
      tile[i][tx] = W[(size_t)(k0 + i) * DMODEL + n0 + tx];
    __syncthreads();
    #pragma unroll
    for (int i = ty; i < 32; i += 8)
      WT[(size_t)(n0 + i) * DMODEL + k0 + tx] = (__bf16)tile[tx][i];
  }
}

// ---------------- batched projection GEMM (bf16 A), 128x128 BK=32, XCD row-pinned (r15 proven) ----------------
__global__ __launch_bounds__(256) void k_gemm_qkv(
    const __bf16* __restrict__ A0, const __bf16* __restrict__ A1, const __bf16* __restrict__ A2,
    const __bf16* __restrict__ W0, const __bf16* __restrict__ W1, const __bf16* __restrict__ W2,
    const float* __restrict__ bi0, const float* __restrict__ bi1, const float* __restrict__ bi2,
    __bf16* __restrict__ C0, __bf16* __restrict__ C1, __bf16* __restrict__ C2) {
  const int z = blockIdx.z;
  const __bf16* A  = z == 0 ? A0 : (z == 1 ? A1 : A2);
  const __bf16* BT = z == 0 ? W0 : (z == 1 ? W1 : W2);
  const float* bias = z == 0 ? bi0 : (z == 1 ? bi1 : bi2);
  __bf16* Cout = z == 0 ? C0 : (z == 1 ? C1 : C2);

  __shared__ __align__(16) __bf16 As[128 * 32];
  __shared__ __align__(16) __bf16 Bs[128 * 32];
  const int tid = threadIdx.x;
  const int lane = tid & 63;
  const int wv = tid >> 6;
  const int wm = wv >> 1, wn = wv & 1;
  const int m0 = (blockIdx.x + 8 * (blockIdx.y >> 3)) * 128;
  const int n0 = (blockIdx.y & 7) * 128;
  const int lr = lane & 15, lg = lane >> 4;

  f32x4 acc[4][4] = {};

  for (int k0 = 0; k0 < KDIM; k0 += 32) {
    #pragma unroll
    for (int i = 0; i < 2; ++i) {
      int c = tid + i * 256;
      int row = c >> 2, seg = c & 3;
      gl2lds16(A + (size_t)(m0 + row) * KDIM + k0 + seg * 8, (char*)As + c * 16);
      gl2lds16(BT + (size_t)(n0 + row) * KDIM + k0 + seg * 8, (char*)Bs + c * 16);
    }
    DRAIN_VM_LGKM();
    __syncthreads();
    bf16x8 af[4], bfr[4];
    #pragma unroll
    for (int mi = 0; mi < 4; ++mi)
      af[mi] = *(const bf16x8*)&As[(wm * 64 + mi * 16 + lr) * 32 + lg * 8];
    #pragma unroll
    for (int ni = 0; ni < 4; ++ni)
      bfr[ni] = *(const bf16x8*)&Bs[(wn * 64 + ni * 16 + lr) * 32 + lg * 8];
    #pragma unroll
    for (int mi = 0; mi < 4; ++mi)
      #pragma unroll
      for (int ni = 0; ni < 4; ++ni)
        acc[mi][ni] = __builtin_amdgcn_mfma_f32_16x16x32_bf16(af[mi], bfr[ni], acc[mi][ni], 0, 0, 0);
    DRAIN_LGKM();
    __syncthreads();
  }

  #pragma unroll
  for (int mi = 0; mi < 4; ++mi)
    #pragma unroll
    for (int ni = 0; ni < 4; ++ni) {
      const int col = n0 + wn * 64 + ni * 16 + lr;
      const float bv = bias[col];
      #pragma unroll
      for (int r = 0; r < 4; ++r) {
        const int row = m0 + wm * 64 + mi * 16 + lg * 4 + r;
        float v = acc[mi][ni][r] + bv;
        const int b = row >> 11, s = row & (SEQ - 1);
        const int h = col >> 6, dd = col & (DK - 1);
        if (z == 2)
          Cout[((size_t)(b * NHEAD + h) * DK + dd) * SEQ + s] = (__bf16)v;
        else
          Cout[((size_t)(b * NHEAD + h) * SEQ + s) * DK + dd] = (__bf16)v;
      }
    }
}

// ---------------- final GEMM + fused merge: C = merge(Op0,Op1) @ WTo + bias ----------------
// Merge folded into A-staging: per-block scale table (128 rows x 16 heads x 2)
// precomputed in LDS once; A-tile = s0*Op0 + s1*Op1 combined in registers then
// ds_write (reg-staged A; B via gl2lds). Kills k_merge kernel + Oh round-trip.
__global__ __launch_bounds__(256) void k_gemm_out(const __bf16* __restrict__ Op0,
                                                  const __bf16* __restrict__ Op1,
                                                  const float* __restrict__ ML,
                                                  const __bf16* __restrict__ BT,
                                                  const float* __restrict__ bias,
                                                  float* __restrict__ Cout) {
  __shared__ __align__(16) __bf16 As[128 * 32];
  __shared__ __align__(16) __bf16 Bs[128 * 32];
  __shared__ float scl[NHEAD][128][2];   // 16KB
  const int tid = threadIdx.x;
  const int lane = tid & 63;
  const int wv = tid >> 6;
  const int wm = wv >> 1, wn = wv & 1;
  const int m0 = (blockIdx.x + 8 * (blockIdx.y >> 3)) * 128;
  const int n0 = (blockIdx.y & 7) * 128;
  const int lr = lane & 15, lg = lane >> 4;

  // ---- per-row/head merge scales (one-time) ----
  for (int p = tid; p < 128 * NHEAD; p += 256) {
    const int row = p >> 4, h = p & 15;
    const int grow = m0 + row;
    const int b = grow >> 11, sr = grow & (SEQ - 1);
    const int ri = (b * NHEAD + h) * SEQ + sr;
    const float m0v = ML[ri],          l0v = ML[65536 + ri];
    const float m1v = ML[131072 + ri], l1v = ML[196608 + ri];
    const float M = fmaxf(m0v, m1v);
    const float w0 = exp2f(m0v - M), w1 = exp2f(m1v - M);
    const float inv = 1.f / (l0v * w0 + l1v * w1);
    scl[h][row][0] = w0 * inv;
    scl[h][row][1] = w1 * inv;
  }
  __syncthreads();

  f32x4 acc[4][4] = {};

  for (int k0 = 0; k0 < KDIM; k0 += 32) {
    const int h = k0 >> 6;
    #pragma unroll
    for (int i = 0; i < 2; ++i) {
      int c = tid + i * 256;
      int row = c >> 2, seg = c & 3;
      gl2lds16(BT + (size_t)(n0 + row) * KDIM + k0 + seg * 8, (char*)Bs + c * 16);
    }
    #pragma unroll
    for (int i = 0; i < 2; ++i) {
      const int c = tid + i * 256;
      const int row = c >> 2, seg = c & 3;
      const size_t off = (size_t)(m0 + row) * KDIM + k0 + seg * 8;
      const bf16x8 a0 = *(const bf16x8*)&Op0[off];
      const bf16x8 a1 = *(const bf16x8*)&Op1[off];
      const float s0 = scl[h][row][0], s1 = scl[h][row][1];
      bf16x8 av;
      #pragma unroll
      for (int j = 0; j < 8; ++j)
        av[j] = (__bf16)((float)a0[j] * s0 + (float)a1[j] * s1);
      *(bf16x8*)((char*)As + c * 16) = av;
    }
    DRAIN_VM_LGKM();
    __syncthreads();
    bf16x8 af[4], bfr[4];
    #pragma unroll
    for (int mi = 0; mi < 4; ++mi)
      af[mi] = *(const bf16x8*)&As[(wm * 64 + mi * 16 + lr) * 32 + lg * 8];
    #pragma unroll
    for (int ni = 0; ni < 4; ++ni)
      bfr[ni] = *(const bf16x8*)&Bs[(wn * 64 + ni * 16 + lr) * 32 + lg * 8];
    #pragma unroll
    for (int mi = 0; mi < 4; ++mi)
      #pragma unroll
      for (int ni = 0; ni < 4; ++ni)
        acc[mi][ni] = __builtin_amdgcn_mfma_f32_16x16x32_bf16(af[mi], bfr[ni], acc[mi][ni], 0, 0, 0);
    DRAIN_LGKM();
    __syncthreads();
  }

  #pragma unroll
  for (int mi = 0; mi < 4; ++mi)
    #pragma unroll
    for (int ni = 0; ni < 4; ++ni) {
      const int col = n0 + wn * 64 + ni * 16 + lr;
      const float bv = bias[col];
      #pragma unroll
      for (int r = 0; r < 4; ++r) {
        const int row = m0 + wm * 64 + mi * 16 + lg * 4 + r;
        Cout[(size_t)row * DMODEL + col] = acc[mi][ni][r] + bv;
      }
    }
}

// ---------------- flash attention (causal), split-2 KV, KVBLK=64, 4 blocks/CU (r16 exact) ----------------
__global__ __launch_bounds__(256, 4) void k_attn(const __bf16* __restrict__ Q,
                                                 const __bf16* __restrict__ Kt,
                                                 const __bf16* __restrict__ Vt,
                                                 const float* __restrict__ pmask,
                                                 __bf16* __restrict__ Op0,
                                                 __bf16* __restrict__ Op1,
                                                 float* __restrict__ ML) {
  __shared__ __align__(16) __bf16 Ks[2][64 * 64];   // 2 x 8KB
  __shared__ __align__(16) __bf16 Vs[2][64 * 64];   // 2 x 8KB
  __shared__ __align__(16) __bf16 plds[4][16 * 64]; // 4 x 2KB wave-private

  const int tid = threadIdx.x;
  const int lane = tid & 63, wv = tid >> 6;
  const int lr = lane & 15, lg = lane >> 4;

  const int bid = blockIdx.x;
  const int xcd = bid & 7;
  const int rdec = bid >> 3;      // 0..127
  const int slot = rdec >> 5;     // 0..3
  const int rem = rdec & 31;
  const int pair = rem >> 1;      // 0..15
  const int s = rem & 1;          // KV subset
  const int bh = slot * 8 + xcd;
  const int b = bh >> 4, h = bh & 15;

  const __bf16* Qb = Q + (size_t)bh * SEQ * DK;
  const __bf16* Kb = Kt + (size_t)bh * SEQ * DK;
  const __bf16* Vb = Vt + (size_t)bh * DK * SEQ;
  const float* pm = pmask + (size_t)b * SEQ;
  __bf16* Op = s ? Op1 : Op0;
  const float SCL = 0.125f * 1.44269504f;   // 1/sqrt(dk) * log2(e)
  const float L2E = 1.44269504f;

  bf16x8 ones;
  #pragma unroll
  for (int i = 0; i < 8; ++i) ones[i] = (__bf16)1.0f;

  auto stage = [&](int buf, int t) {
    #pragma unroll
    for (int i = 0; i < 2; ++i) {
      const int c = tid + i * 256;              // 512 x 16B chunks
      const int row = c >> 3;                   // 0..63
      const int sx = ((c & 7) * 16) ^ ((row & 7) << 4);
      gl2lds16((const char*)Kb + (size_t)(t * 64 + row) * 128 + sx,
               (char*)&Ks[buf][0] + c * 16);
      gl2lds16((const char*)Vb + (size_t)row * (SEQ * 2) + (size_t)t * 128 + sx,
               (char*)&Vs[buf][0] + c * 16);
    }
  };

  for (int half = 0; half < 2; ++half) {
    const int qb = half ? (31 - pair) : pair;   // 64-row Q chunk index
    const int nt = qb + 1;                      // causal 64-wide KV tiles
    const int QR = qb * 64 + wv * 16;           // this wave's first Q row

    const bf16x8 qf0 = *(const bf16x8*)&Qb[(size_t)(QR + lr) * DK + lg * 8];
    const bf16x8 qf1 = *(const bf16x8*)&Qb[(size_t)(QR + lr) * DK + 32 + lg * 8];

    float mrow = -1e30f;              // q-row = lr (log2 domain)
    f32x4 lacc = {0.f, 0.f, 0.f, 0.f};// l per row q = lg*4+r (MFMA layout)
    f32x4 oacc[4] = {};               // [og]: row q=lg*4+r, col d=og*16+lr

    int t = s;
    if (t < nt) {
      stage(0, t);
      DRAIN_VM_LGKM();
      __syncthreads();
    }
    int cur = 0;
    for (; t < nt; t += 2) {
      if (t + 2 < nt) stage(cur ^ 1, t + 2);
      // ---- S^T = K Q^T (K-frags from swizzled LDS) ----
      f32x4 sc[4];
      #pragma unroll
      for (int g = 0; g < 4; ++g) {
        const int krow = g * 16 + lr;
        const int ksw = (lr & 7) << 4;
        bf16x8 kf0 = *(const bf16x8*)((const char*)&Ks[cur][0] + krow * 128 + ((lg * 16) ^ ksw));
        bf16x8 kf1 = *(const bf16x8*)((const char*)&Ks[cur][0] + krow * 128 + ((64 + lg * 16) ^ ksw));
        f32x4 a = {};
        a = __builtin_amdgcn_mfma_f32_16x16x32_bf16(kf0, qf0, a, 0, 0, 0);
        a = __builtin_amdgcn_mfma_f32_16x16x32_bf16(kf1, qf1, a, 0, 0, 0);
        sc[g] = a;   // sc[g][r] = S[q=QR+lr][kv=t*64+g*16+lg*4+r]
      }
      // ---- scale + padding + causal masks (log2 domain) ----
      const bool edge = (t == qb);
      #pragma unroll
      for (int g = 0; g < 4; ++g) {
        const float4 pmv = *(const float4*)&pm[t * 64 + g * 16 + lg * 4];
        const float pmf[4] = {pmv.x, pmv.y, pmv.z, pmv.w};
        #pragma unroll
        for (int r = 0; r < 4; ++r) {
          float sv = sc[g][r] * SCL + pmf[r] * L2E;
          if (edge && (t * 64 + g * 16 + lg * 4 + r > QR + lr)) sv = -1e30f;
          sc[g][r] = sv;
        }
      }
      // ---- online softmax max-track, defer-max (T13) ----
      float pmax = sc[0][0];
      #pragma unroll
      for (int g = 0; g < 4; ++g)
        #pragma unroll
        for (int r = 0; r < 4; ++r) pmax = fmaxf(pmax, sc[g][r]);
      pmax = fmaxf(pmax, __shfl_xor(pmax, 16, 64));
      pmax = fmaxf(pmax, __shfl_xor(pmax, 32, 64));
      if (!__all(pmax <= mrow + 8.f)) {
        const float mnew = fmaxf(mrow, pmax);
        const float alpha = exp2f(mrow - mnew);
        mrow = mnew;
        #pragma unroll
        for (int r = 0; r < 4; ++r) {
          const float av = __shfl(alpha, lg * 4 + r, 64);
          lacc[r] *= av;
          #pragma unroll
          for (int og = 0; og < 4; ++og) oacc[og][r] *= av;
        }
      }
      #pragma unroll
      for (int g = 0; g < 4; ++g)
        #pragma unroll
        for (int r = 0; r < 4; ++r)
          sc[g][r] = exp2f(sc[g][r] - mrow);
      // ---- P -> wave-private LDS (bf16, XOR swizzle (row&7)<<4) ----
      #pragma unroll
      for (int g = 0; g < 4; ++g) {
        bf16x4 pk = { (__bf16)sc[g][0], (__bf16)sc[g][1], (__bf16)sc[g][2], (__bf16)sc[g][3] };
        const int byteoff = lr * 128 + ((g * 32 + lg * 8) ^ ((lr & 7) << 4));
        *(bf16x4*)((char*)plds[wv] + byteoff) = pk;
      }
      // ---- PV: O += P V; l += P·1 (MFMA row-sum, ones B-frag) ----
      f32x4 ps = {0.f, 0.f, 0.f, 0.f};
      #pragma unroll
      for (int kk = 0; kk < 2; ++kk) {
        const int pboff = lr * 128 + ((kk * 64 + lg * 16) ^ ((lr & 7) << 4));
        const bf16x8 pa = *(const bf16x8*)((char*)plds[wv] + pboff);
        ps = __builtin_amdgcn_mfma_f32_16x16x32_bf16(pa, ones, ps, 0, 0, 0);
        #pragma unroll
        for (int og = 0; og < 4; ++og) {
          const int vrow = og * 16 + lr;
          const int vsw = (vrow & 7) << 4;
          const bf16x8 vf = *(const bf16x8*)((const char*)&Vs[cur][0] + vrow * 128 + ((kk * 64 + lg * 16) ^ vsw));
          oacc[og] = __builtin_amdgcn_mfma_f32_16x16x32_bf16(pa, vf, oacc[og], 0, 0, 0);
        }
      }
      lacc += ps;
      DRAIN_VM_LGKM();   // staged loads landed (RAW) + ds ops done (WAR)
      __syncthreads();
      cur ^= 1;
    }

    // ---- epilogue: write UN-normalized bf16 partial O + per-row m,l ----
    #pragma unroll
    for (int r = 0; r < 4; ++r) {
      const int row = QR + lg * 4 + r;
      #pragma unroll
      for (int og = 0; og < 4; ++og)
        Op[((size_t)b * SEQ + row) * DMODEL + h * DK + og * 16 + lr] = (__bf16)oacc[og][r];
    }
    if (lg == 0)
      ML[s * 131072 + bh * SEQ + QR + lr] = mrow;
    if (lr == 0) {
      #pragma unroll
      for (int r = 0; r < 4; ++r)
        ML[s * 131072 + 65536 + bh * SEQ + QR + lg * 4 + r] = lacc[r];
    }
  }
}

extern "C" void kernel_launch(void* const* d_in, const int* in_sizes, int n_in,
                              void* d_out, int out_size, void* d_ws, size_t ws_size,
                              hipStream_t stream) {
  (void)in_sizes; (void)n_in; (void)out_size; (void)ws_size;
  const float* query = (const float*)d_in[0];
  const float* key   = (const float*)d_in[1];
  const float* value = (const float*)d_in[2];
  const float* pmask = (const float*)d_in[3];
  const float* w_q = (const float*)d_in[5];
  const float* w_k = (const float*)d_in[6];
  const float* w_v = (const float*)d_in[7];
  const float* w_o = (const float*)d_in[8];
  const float* b_q = (const float*)d_in[9];
  const float* b_k = (const float*)d_in[10];
  const float* b_v = (const float*)d_in[11];
  const float* b_o = (const float*)d_in[12];

  __bf16* ws = (__bf16*)d_ws;
  const size_t WSZ = (size_t)DMODEL * DMODEL;  // 1M elems
  const size_t XSZ = (size_t)MTOT * DMODEL;    // 4M elems
  __bf16* WTq = ws;
  __bf16* WTk = WTq + WSZ;
  __bf16* WTv = WTk + WSZ;
  __bf16* WTo = WTv + WSZ;
  __bf16* Xq  = WTo + WSZ;
  __bf16* Xk  = Xq + XSZ;
  __bf16* Xv  = Xk + XSZ;
  __bf16* Qh  = Xv + XSZ;
  __bf16* Kh  = Qh + XSZ;
  __bf16* Vh  = Kh + XSZ;
  __bf16* Op0 = Xk;                    // bf16 partials: alias Xk/Xv (dead after qkv)
  __bf16* Op1 = Xv;
  float*  MLb = (float*)(Vh + XSZ);    // 1MB fresh

  dim3 blk(256);
  k_prep<<<dim3(7168), blk, 0, stream>>>(query, key, value, Xq, Xk, Xv,
                                         w_q, w_k, w_v, w_o, WTq, WTk, WTv, WTo);

  k_gemm_qkv<<<dim3(8, 32, 3), blk, 0, stream>>>(Xq, Xk, Xv, WTq, WTk, WTv,
                                                 b_q, b_k, b_v, Qh, Kh, Vh);

  k_attn<<<dim3(1024), blk, 0, stream>>>(Qh, Kh, Vh, pmask, Op0, Op1, MLb);

  k_gemm_out<<<dim3(8, 32), blk, 0, stream>>>(Op0, Op1, MLb, WTo, b_o, (float*)d_out);
}

// Round 18
// 143.535 us; speedup vs baseline: 1.0675x; 1.0675x over previous
//
#include <hip/hip_runtime.h>
#include <hip/hip_bf16.h>
#include <stdint.h>

typedef __bf16 bf16x8 __attribute__((ext_vector_type(8)));
typedef __bf16 bf16x4 __attribute__((ext_vector_type(4)));
typedef float f32x4 __attribute__((ext_vector_type(4)));

#define DMODEL 1024
#define SEQ    2048
#define NHEAD  16
#define DK     64
#define MTOT   4096
#define KDIM   1024

#define DRAIN_VM_LGKM() asm volatile("s_waitcnt vmcnt(0) lgkmcnt(0)" ::: "memory")
#define DRAIN_LGKM()    asm volatile("s_waitcnt lgkmcnt(0)" ::: "memory")

__device__ __forceinline__ void gl2lds16(const void* g, void* l) {
  __builtin_amdgcn_global_load_lds((__attribute__((address_space(1))) void*)(g),
                                   (__attribute__((address_space(3))) void*)(l),
                                   16, 0, 0);
}

// ---------------- prep: cvt3 grid-stride (blocks 0..3071) + transpose4 (3072..7167) ----------------
__global__ __launch_bounds__(256) void k_prep(const float* __restrict__ q,
                                              const float* __restrict__ k,
                                              const float* __restrict__ v,
                                              __bf16* __restrict__ oq,
                                              __bf16* __restrict__ ok,
                                              __bf16* __restrict__ ov,
                                              const float* __restrict__ w0,
                                              const float* __restrict__ w1,
                                              const float* __restrict__ w2,
                                              const float* __restrict__ w3,
                                              __bf16* __restrict__ t0,
                                              __bf16* __restrict__ t1,
                                              __bf16* __restrict__ t2,
                                              __bf16* __restrict__ t3) {
  __shared__ float tile[32][33];
  const int bid = blockIdx.x;
  if (bid < 3072) {                        // f32 -> bf16 convert, q/k/v (grid-stride x4)
    const int which = bid >> 10;           // 0..2
    const float* in = which == 0 ? q : (which == 1 ? k : v);
    __bf16* out = which == 0 ? oq : (which == 1 ? ok : ov);
    int i = (bid & 1023) * 256 + threadIdx.x;   // 1M float4 per input
    #pragma unroll
    for (int it = 0; it < 4; ++it, i += 262144) {
      const float4 f = ((const float4*)in)[i];
      bf16x4 o = { (__bf16)f.x, (__bf16)f.y, (__bf16)f.z, (__bf16)f.w };
      ((bf16x4*)out)[i] = o;
    }
  } else {                                 // W [K][N] f32 -> WT [N][K] bf16
    const int b2 = bid - 3072;             // 0..4095
    const int z = b2 >> 10;
    const int t = b2 & 1023;
    const float* W = z == 0 ? w0 : (z == 1 ? w1 : (z == 2 ? w2 : w3));
    __bf16* WT = z == 0 ? t0 : (z == 1 ? t1 : (z == 2 ? t2 : t3));
    const int n0 = (t & 31) * 32, k0 = (t >> 5) * 32;
    const int tx = threadIdx.x & 31, ty = threadIdx.x >> 5;
    #pragma unroll
    for (int i = ty; i < 32; i += 8)
      tile[i][tx] = W[(size_t)(k0 + i) * DMODEL + n0 + tx];
    __syncthreads();
    #pragma unroll
    for (int i = ty; i < 32; i += 8)
      WT[(size_t)(n0 + i) * DMODEL + k0 + tx] = (__bf16)tile[tx][i];
  }
}

// ---------------- batched projection GEMM (bf16 A), 128x128 BK=32, XCD row-pinned (r15 proven) ----------------
__global__ __launch_bounds__(256) void k_gemm_qkv(
    const __bf16* __restrict__ A0, const __bf16* __restrict__ A1, const __bf16* __restrict__ A2,
    const __bf16* __restrict__ W0, const __bf16* __restrict__ W1, const __bf16* __restrict__ W2,
    const float* __restrict__ bi0, const float* __restrict__ bi1, const float* __restrict__ bi2,
    __bf16* __restrict__ C0, __bf16* __restrict__ C1, __bf16* __restrict__ C2) {
  const int z = blockIdx.z;
  const __bf16* A  = z == 0 ? A0 : (z == 1 ? A1 : A2);
  const __bf16* BT = z == 0 ? W0 : (z == 1 ? W1 : W2);
  const float* bias = z == 0 ? bi0 : (z == 1 ? bi1 : bi2);
  __bf16* Cout = z == 0 ? C0 : (z == 1 ? C1 : C2);

  __shared__ __align__(16) __bf16 As[128 * 32];
  __shared__ __align__(16) __bf16 Bs[128 * 32];
  const int tid = threadIdx.x;
  const int lane = tid & 63;
  const int wv = tid >> 6;
  const int wm = wv >> 1, wn = wv & 1;
  const int m0 = (blockIdx.x + 8 * (blockIdx.y >> 3)) * 128;
  const int n0 = (blockIdx.y & 7) * 128;
  const int lr = lane & 15, lg = lane >> 4;

  f32x4 acc[4][4] = {};

  for (int k0 = 0; k0 < KDIM; k0 += 32) {
    #pragma unroll
    for (int i = 0; i < 2; ++i) {
      int c = tid + i * 256;
      int row = c >> 2, seg = c & 3;
      gl2lds16(A + (size_t)(m0 + row) * KDIM + k0 + seg * 8, (char*)As + c * 16);
      gl2lds16(BT + (size_t)(n0 + row) * KDIM + k0 + seg * 8, (char*)Bs + c * 16);
    }
    DRAIN_VM_LGKM();
    __syncthreads();
    bf16x8 af[4], bfr[4];
    #pragma unroll
    for (int mi = 0; mi < 4; ++mi)
      af[mi] = *(const bf16x8*)&As[(wm * 64 + mi * 16 + lr) * 32 + lg * 8];
    #pragma unroll
    for (int ni = 0; ni < 4; ++ni)
      bfr[ni] = *(const bf16x8*)&Bs[(wn * 64 + ni * 16 + lr) * 32 + lg * 8];
    #pragma unroll
    for (int mi = 0; mi < 4; ++mi)
      #pragma unroll
      for (int ni = 0; ni < 4; ++ni)
        acc[mi][ni] = __builtin_amdgcn_mfma_f32_16x16x32_bf16(af[mi], bfr[ni], acc[mi][ni], 0, 0, 0);
    DRAIN_LGKM();
    __syncthreads();
  }

  #pragma unroll
  for (int mi = 0; mi < 4; ++mi)
    #pragma unroll
    for (int ni = 0; ni < 4; ++ni) {
      const int col = n0 + wn * 64 + ni * 16 + lr;
      const float bv = bias[col];
      #pragma unroll
      for (int r = 0; r < 4; ++r) {
        const int row = m0 + wm * 64 + mi * 16 + lg * 4 + r;
        float v = acc[mi][ni][r] + bv;
        const int b = row >> 11, s = row & (SEQ - 1);
        const int h = col >> 6, dd = col & (DK - 1);
        if (z == 2)
          Cout[((size_t)(b * NHEAD + h) * DK + dd) * SEQ + s] = (__bf16)v;
        else
          Cout[((size_t)(b * NHEAD + h) * SEQ + s) * DK + dd] = (__bf16)v;
      }
    }
}

// ---------------- final GEMM: f32 out + bias, 128x128 BK=32, XCD row-pinned (r15 proven) ----------------
__global__ __launch_bounds__(256) void k_gemm_out(const __bf16* __restrict__ A,
                                                  const __bf16* __restrict__ BT,
                                                  const float* __restrict__ bias,
                                                  float* __restrict__ Cout) {
  __shared__ __align__(16) __bf16 As[128 * 32];
  __shared__ __align__(16) __bf16 Bs[128 * 32];
  const int tid = threadIdx.x;
  const int lane = tid & 63;
  const int wv = tid >> 6;
  const int wm = wv >> 1, wn = wv & 1;
  const int m0 = (blockIdx.x + 8 * (blockIdx.y >> 3)) * 128;
  const int n0 = (blockIdx.y & 7) * 128;
  const int lr = lane & 15, lg = lane >> 4;

  f32x4 acc[4][4] = {};

  for (int k0 = 0; k0 < KDIM; k0 += 32) {
    #pragma unroll
    for (int i = 0; i < 2; ++i) {
      int c = tid + i * 256;
      int row = c >> 2, seg = c & 3;
      gl2lds16(A + (size_t)(m0 + row) * KDIM + k0 + seg * 8, (char*)As + c * 16);
      gl2lds16(BT + (size_t)(n0 + row) * KDIM + k0 + seg * 8, (char*)Bs + c * 16);
    }
    DRAIN_VM_LGKM();
    __syncthreads();
    bf16x8 af[4], bfr[4];
    #pragma unroll
    for (int mi = 0; mi < 4; ++mi)
      af[mi] = *(const bf16x8*)&As[(wm * 64 + mi * 16 + lr) * 32 + lg * 8];
    #pragma unroll
    for (int ni = 0; ni < 4; ++ni)
      bfr[ni] = *(const bf16x8*)&Bs[(wn * 64 + ni * 16 + lr) * 32 + lg * 8];
    #pragma unroll
    for (int mi = 0; mi < 4; ++mi)
      #pragma unroll
      for (int ni = 0; ni < 4; ++ni)
        acc[mi][ni] = __builtin_amdgcn_mfma_f32_16x16x32_bf16(af[mi], bfr[ni], acc[mi][ni], 0, 0, 0);
    DRAIN_LGKM();
    __syncthreads();
  }

  #pragma unroll
  for (int mi = 0; mi < 4; ++mi)
    #pragma unroll
    for (int ni = 0; ni < 4; ++ni) {
      const int col = n0 + wn * 64 + ni * 16 + lr;
      const float bv = bias[col];
      #pragma unroll
      for (int r = 0; r < 4; ++r) {
        const int row = m0 + wm * 64 + mi * 16 + lg * 4 + r;
        Cout[(size_t)row * DMODEL + col] = acc[mi][ni][r] + bv;
      }
    }
}

// ---------------- flash attention (causal), split-2 KV, KVBLK=64, 4 blocks/CU (r16 proven) ----------------
// MFMA row-sum: l via mfma(P, ones) in the oacc row layout; bf16 partials.
__global__ __launch_bounds__(256, 4) void k_attn(const __bf16* __restrict__ Q,
                                                 const __bf16* __restrict__ Kt,
                                                 const __bf16* __restrict__ Vt,
                                                 const float* __restrict__ pmask,
                                                 __bf16* __restrict__ Op0,
                                                 __bf16* __restrict__ Op1,
                                                 float* __restrict__ ML) {
  __shared__ __align__(16) __bf16 Ks[2][64 * 64];   // 2 x 8KB
  __shared__ __align__(16) __bf16 Vs[2][64 * 64];   // 2 x 8KB
  __shared__ __align__(16) __bf16 plds[4][16 * 64]; // 4 x 2KB wave-private

  const int tid = threadIdx.x;
  const int lane = tid & 63, wv = tid >> 6;
  const int lr = lane & 15, lg = lane >> 4;

  const int bid = blockIdx.x;
  const int xcd = bid & 7;
  const int rdec = bid >> 3;      // 0..127
  const int slot = rdec >> 5;     // 0..3
  const int rem = rdec & 31;
  const int pair = rem >> 1;      // 0..15
  const int s = rem & 1;          // KV subset
  const int bh = slot * 8 + xcd;
  const int b = bh >> 4, h = bh & 15;

  const __bf16* Qb = Q + (size_t)bh * SEQ * DK;
  const __bf16* Kb = Kt + (size_t)bh * SEQ * DK;
  const __bf16* Vb = Vt + (size_t)bh * DK * SEQ;
  const float* pm = pmask + (size_t)b * SEQ;
  __bf16* Op = s ? Op1 : Op0;
  const float SCL = 0.125f * 1.44269504f;   // 1/sqrt(dk) * log2(e)
  const float L2E = 1.44269504f;

  bf16x8 ones;
  #pragma unroll
  for (int i = 0; i < 8; ++i) ones[i] = (__bf16)1.0f;

  auto stage = [&](int buf, int t) {
    #pragma unroll
    for (int i = 0; i < 2; ++i) {
      const int c = tid + i * 256;              // 512 x 16B chunks
      const int row = c >> 3;                   // 0..63
      const int sx = ((c & 7) * 16) ^ ((row & 7) << 4);
      gl2lds16((const char*)Kb + (size_t)(t * 64 + row) * 128 + sx,
               (char*)&Ks[buf][0] + c * 16);
      gl2lds16((const char*)Vb + (size_t)row * (SEQ * 2) + (size_t)t * 128 + sx,
               (char*)&Vs[buf][0] + c * 16);
    }
  };

  for (int half = 0; half < 2; ++half) {
    const int qb = half ? (31 - pair) : pair;   // 64-row Q chunk index
    const int nt = qb + 1;                      // causal 64-wide KV tiles
    const int QR = qb * 64 + wv * 16;           // this wave's first Q row

    const bf16x8 qf0 = *(const bf16x8*)&Qb[(size_t)(QR + lr) * DK + lg * 8];
    const bf16x8 qf1 = *(const bf16x8*)&Qb[(size_t)(QR + lr) * DK + 32 + lg * 8];

    float mrow = -1e30f;              // q-row = lr (log2 domain)
    f32x4 lacc = {0.f, 0.f, 0.f, 0.f};// l per row q = lg*4+r (MFMA layout)
    f32x4 oacc[4] = {};               // [og]: row q=lg*4+r, col d=og*16+lr

    int t = s;
    if (t < nt) {
      stage(0, t);
      DRAIN_VM_LGKM();
      __syncthreads();
    }
    int cur = 0;
    for (; t < nt; t += 2) {
      if (t + 2 < nt) stage(cur ^ 1, t + 2);
      // ---- S^T = K Q^T (K-frags from swizzled LDS) ----
      f32x4 sc[4];
      #pragma unroll
      for (int g = 0; g < 4; ++g) {
        const int krow = g * 16 + lr;
        const int ksw = (lr & 7) << 4;
        bf16x8 kf0 = *(const bf16x8*)((const char*)&Ks[cur][0] + krow * 128 + ((lg * 16) ^ ksw));
        bf16x8 kf1 = *(const bf16x8*)((const char*)&Ks[cur][0] + krow * 128 + ((64 + lg * 16) ^ ksw));
        f32x4 a = {};
        a = __builtin_amdgcn_mfma_f32_16x16x32_bf16(kf0, qf0, a, 0, 0, 0);
        a = __builtin_amdgcn_mfma_f32_16x16x32_bf16(kf1, qf1, a, 0, 0, 0);
        sc[g] = a;   // sc[g][r] = S[q=QR+lr][kv=t*64+g*16+lg*4+r]
      }
      // ---- scale + padding + causal masks (log2 domain) ----
      const bool edge = (t == qb);
      #pragma unroll
      for (int g = 0; g < 4; ++g) {
        const float4 pmv = *(const float4*)&pm[t * 64 + g * 16 + lg * 4];
        const float pmf[4] = {pmv.x, pmv.y, pmv.z, pmv.w};
        #pragma unroll
        for (int r = 0; r < 4; ++r) {
          float sv = sc[g][r] * SCL + pmf[r] * L2E;
          if (edge && (t * 64 + g * 16 + lg * 4 + r > QR + lr)) sv = -1e30f;
          sc[g][r] = sv;
        }
      }
      // ---- online softmax max-track, defer-max (T13) ----
      float pmax = sc[0][0];
      #pragma unroll
      for (int g = 0; g < 4; ++g)
        #pragma unroll
        for (int r = 0; r < 4; ++r) pmax = fmaxf(pmax, sc[g][r]);
      pmax = fmaxf(pmax, __shfl_xor(pmax, 16, 64));
      pmax = fmaxf(pmax, __shfl_xor(pmax, 32, 64));
      if (!__all(pmax <= mrow + 8.f)) {
        const float mnew = fmaxf(mrow, pmax);
        const float alpha = exp2f(mrow - mnew);
        mrow = mnew;
        #pragma unroll
        for (int r = 0; r < 4; ++r) {
          const float av = __shfl(alpha, lg * 4 + r, 64);
          lacc[r] *= av;
          #pragma unroll
          for (int og = 0; og < 4; ++og) oacc[og][r] *= av;
        }
      }
      #pragma unroll
      for (int g = 0; g < 4; ++g)
        #pragma unroll
        for (int r = 0; r < 4; ++r)
          sc[g][r] = exp2f(sc[g][r] - mrow);
      // ---- P -> wave-private LDS (bf16, XOR swizzle (row&7)<<4) ----
      #pragma unroll
      for (int g = 0; g < 4; ++g) {
        bf16x4 pk = { (__bf16)sc[g][0], (__bf16)sc[g][1], (__bf16)sc[g][2], (__bf16)sc[g][3] };
        const int byteoff = lr * 128 + ((g * 32 + lg * 8) ^ ((lr & 7) << 4));
        *(bf16x4*)((char*)plds[wv] + byteoff) = pk;
      }
      // ---- PV: O += P V; l += P·1 (MFMA row-sum, ones B-frag) ----
      f32x4 ps = {0.f, 0.f, 0.f, 0.f};
      #pragma unroll
      for (int kk = 0; kk < 2; ++kk) {
        const int pboff = lr * 128 + ((kk * 64 + lg * 16) ^ ((lr & 7) << 4));
        const bf16x8 pa = *(const bf16x8*)((char*)plds[wv] + pboff);
        ps = __builtin_amdgcn_mfma_f32_16x16x32_bf16(pa, ones, ps, 0, 0, 0);
        #pragma unroll
        for (int og = 0; og < 4; ++og) {
          const int vrow = og * 16 + lr;
          const int vsw = (vrow & 7) << 4;
          const bf16x8 vf = *(const bf16x8*)((const char*)&Vs[cur][0] + vrow * 128 + ((kk * 64 + lg * 16) ^ vsw));
          oacc[og] = __builtin_amdgcn_mfma_f32_16x16x32_bf16(pa, vf, oacc[og], 0, 0, 0);
        }
      }
      lacc += ps;
      DRAIN_VM_LGKM();   // staged loads landed (RAW) + ds ops done (WAR)
      __syncthreads();
      cur ^= 1;
    }

    // ---- epilogue: write UN-normalized bf16 partial O + per-row m,l ----
    #pragma unroll
    for (int r = 0; r < 4; ++r) {
      const int row = QR + lg * 4 + r;
      #pragma unroll
      for (int og = 0; og < 4; ++og)
        Op[((size_t)b * SEQ + row) * DMODEL + h * DK + og * 16 + lr] = (__bf16)oacc[og][r];
    }
    if (lg == 0)
      ML[s * 131072 + bh * SEQ + QR + lr] = mrow;
    if (lr == 0) {
      #pragma unroll
      for (int r = 0; r < 4; ++r)
        ML[s * 131072 + 65536 + bh * SEQ + QR + lg * 4 + r] = lacc[r];
    }
  }
}

// ---------------- merge two KV-subset bf16 partials -> bf16 O ----------------
__global__ __launch_bounds__(256) void k_merge(const __bf16* __restrict__ Op0,
                                               const __bf16* __restrict__ Op1,
                                               const float* __restrict__ ML,
                                               __bf16* __restrict__ Oh) {
  const int idx = blockIdx.x * 256 + threadIdx.x;  // 1M threads, 4 elems each
  const int row = idx >> 8;          // 0..4095 (B*S)
  const int col = (idx & 255) * 4;   // 0..1020
  const int b = row >> 11, sr = row & (SEQ - 1);
  const int h = col >> 6;
  const int ri = (b * NHEAD + h) * SEQ + sr;
  const float m0 = ML[ri], l0 = ML[65536 + ri];
  const float m1 = ML[131072 + ri], l1 = ML[196608 + ri];
  const float M = fmaxf(m0, m1);
  const float w0 = exp2f(m0 - M), w1 = exp2f(m1 - M);
  const float inv = 1.f / (l0 * w0 + l1 * w1);
  const float s0 = w0 * inv, s1 = w1 * inv;
  const size_t off = (size_t)row * DMODEL + col;
  const bf16x4 o0 = *(const bf16x4*)&Op0[off];
  const bf16x4 o1 = *(const bf16x4*)&Op1[off];
  bf16x4 o = { (__bf16)((float)o0[0] * s0 + (float)o1[0] * s1),
               (__bf16)((float)o0[1] * s0 + (float)o1[1] * s1),
               (__bf16)((float)o0[2] * s0 + (float)o1[2] * s1),
               (__bf16)((float)o0[3] * s0 + (float)o1[3] * s1) };
  *(bf16x4*)&Oh[off] = o;
}

extern "C" void kernel_launch(void* const* d_in, const int* in_sizes, int n_in,
                              void* d_out, int out_size, void* d_ws, size_t ws_size,
                              hipStream_t stream) {
  (void)in_sizes; (void)n_in; (void)out_size; (void)ws_size;
  const float* query = (const float*)d_in[0];
  const float* key   = (const float*)d_in[1];
  const float* value = (const float*)d_in[2];
  const float* pmask = (const float*)d_in[3];
  const float* w_q = (const float*)d_in[5];
  const float* w_k = (const float*)d_in[6];
  const float* w_v = (const float*)d_in[7];
  const float* w_o = (const float*)d_in[8];
  const float* b_q = (const float*)d_in[9];
  const float* b_k = (const float*)d_in[10];
  const float* b_v = (const float*)d_in[11];
  const float* b_o = (const float*)d_in[12];

  __bf16* ws = (__bf16*)d_ws;
  const size_t WSZ = (size_t)DMODEL * DMODEL;  // 1M elems
  const size_t XSZ = (size_t)MTOT * DMODEL;    // 4M elems
  __bf16* WTq = ws;
  __bf16* WTk = WTq + WSZ;
  __bf16* WTv = WTk + WSZ;
  __bf16* WTo = WTv + WSZ;
  __bf16* Xq  = WTo + WSZ;
  __bf16* Xk  = Xq + XSZ;
  __bf16* Xv  = Xk + XSZ;
  __bf16* Qh  = Xv + XSZ;
  __bf16* Kh  = Qh + XSZ;
  __bf16* Vh  = Kh + XSZ;
  __bf16* Op0 = Xk;                    // bf16 partials: alias Xk/Xv (dead after qkv)
  __bf16* Op1 = Xv;
  float*  MLb = (float*)(Vh + XSZ);    // 1MB fresh
  __bf16* Oh  = Xq;                    // merge output: aliases Xq (dead after qkv)

  dim3 blk(256);
  k_prep<<<dim3(7168), blk, 0, stream>>>(query, key, value, Xq, Xk, Xv,
                                         w_q, w_k, w_v, w_o, WTq, WTk, WTv, WTo);

  k_gemm_qkv<<<dim3(8, 32, 3), blk, 0, stream>>>(Xq, Xk, Xv, WTq, WTk, WTv,
                                                 b_q, b_k, b_v, Qh, Kh, Vh);

  k_attn<<<dim3(1024), blk, 0, stream>>>(Qh, Kh, Vh, pmask, Op0, Op1, MLb);
  k_merge<<<dim3(4096), blk, 0, stream>>>(Op0, Op1, MLb, Oh);

  k_gemm_out<<<dim3(8, 32), blk, 0, stream>>>(Oh, WTo, b_o, (float*)d_out);
}